// Round 6
// baseline (390.996 us; speedup 1.0000x reference)
//
#include <hip/hip_runtime.h>
#include <hip/hip_bf16.h>
#include <math.h>

// ---------------------------------------------------------------------------
// WavLM self-attention, bf16-MFMA v5.
//   B=8 S=1024 H=16 D=64 E=1024; q pre-scaled by 0.125*log2(e) (exp2 softmax)
// Round-6 changes vs validated round-5:
//   * attn: K & V single-buffered -> LDS 37.25 KB -> 4 blocks/CU (32 waves/CU),
//     grid 1024 = exactly 4/CU (single round, no tail); gates LDS removed
//     (per-thread global scalar); epilogue barrier removed.
//   * gemm_qkv: __launch_bounds__(256,5) -> VGPR cap 102 -> 5 blocks/CU.
//   * everything else unchanged (validated round-5 code).
// Workspace (bytes): same layout as round-3/4/5.
// ---------------------------------------------------------------------------

typedef __attribute__((ext_vector_type(8))) short short8;
typedef __attribute__((ext_vector_type(4))) float f32x4;

#define LDSP(p) ((__attribute__((address_space(3))) void*)(p))
#define GLBP(p) ((const __attribute__((address_space(1))) void*)(p))

__device__ __forceinline__ void async_ld16(const void* src, void* dst) {
  __builtin_amdgcn_global_load_lds(GLBP(src), LDSP(dst), 16, 0, 0);
}
__device__ __forceinline__ unsigned short f2bf(float f) {
  __hip_bfloat16 h = __float2bfloat16(f);
  return __builtin_bit_cast(unsigned short, h);
}
#if __has_builtin(__builtin_amdgcn_exp2f)
#define EXP2(x) __builtin_amdgcn_exp2f(x)
#else
#define EXP2(x) exp2f(x)
#endif

// ---------------------------------------------------------------------------
// Fused prep: [0,8192) cvt+gate, [8192,9216) transW x4, [9216,9224) btab.
// (unchanged, validated)
// ---------------------------------------------------------------------------
__global__ __launch_bounds__(256) void prep_all(
    const float* __restrict__ x, const float* __restrict__ gw,
    const float* __restrict__ gb, const float* __restrict__ gcst,
    const float* __restrict__ W0, const float* __restrict__ W1,
    const float* __restrict__ W2, const float* __restrict__ W3,
    const float* __restrict__ rel_embed,
    unsigned short* __restrict__ xb, float* __restrict__ gate_ws,
    unsigned short* __restrict__ Wt_all, float* __restrict__ btab) {
  __shared__ __align__(16) float tile[64][68];
  const int bid = blockIdx.x, t = threadIdx.x;
  if (bid < 8192) {
    float* xr = &tile[0][0];
    const float4 v = *(const float4*)&x[(size_t)bid * 1024 + t * 4];
    *(float4*)&xr[t * 4] = v;
    ushort4 o;
    o.x = f2bf(v.x); o.y = f2bf(v.y); o.z = f2bf(v.z); o.w = f2bf(v.w);
    *(ushort4*)&xb[(size_t)bid * 1024 + t * 4] = o;
    __syncthreads();
    const int h = t >> 4, i = t & 15;
    float pa = 0.f, pb = 0.f;
    #pragma unroll
    for (int j = 0; j < 4; ++j) {
      const int d = i * 4 + j;
      const float xv = xr[h * 64 + d];
      const float* wr = &gw[d * 8];
      pa += xv * (wr[0] + wr[1] + wr[2] + wr[3]);
      pb += xv * (wr[4] + wr[5] + wr[6] + wr[7]);
    }
    #pragma unroll
    for (int msk = 1; msk <= 8; msk <<= 1) {
      pa += __shfl_xor(pa, msk);
      pb += __shfl_xor(pb, msk);
    }
    if (i == 0) {
      const float ba = gb[0] + gb[1] + gb[2] + gb[3];
      const float bb = gb[4] + gb[5] + gb[6] + gb[7];
      const float ga  = 1.f / (1.f + __expf(-(pa + ba)));
      const float gbv = 1.f / (1.f + __expf(-(pb + bb)));
      const float gv  = ga * (gbv * gcst[h] - 1.f) + 2.f;
      const int b = bid >> 10, s = bid & 1023;
      gate_ws[(b * 16 + h) * 1024 + s] = gv;
    }
  } else if (bid < 9216) {
    const int zz = bid - 8192;
    const int z = zz >> 8;
    const float* W = (z == 0) ? W0 : (z == 1) ? W1 : (z == 2) ? W2 : W3;
    unsigned short* Wt = Wt_all + (size_t)z * 1048576;
    const int n0 = (zz & 15) * 64, k0 = ((zz >> 4) & 15) * 64;
    const int c = (t & 15) * 4, r = t >> 4;
    #pragma unroll
    for (int i = 0; i < 4; ++i)
      *(float4*)&tile[r + i * 16][c] =
          *(const float4*)&W[(size_t)(k0 + r + i * 16) * 1024 + n0 + c];
    __syncthreads();
    #pragma unroll
    for (int i = 0; i < 4; ++i) {
      const int n = r + i * 16;
      ushort4 o;
      o.x = f2bf(tile[c + 0][n]); o.y = f2bf(tile[c + 1][n]);
      o.z = f2bf(tile[c + 2][n]); o.w = f2bf(tile[c + 3][n]);
      *(ushort4*)&Wt[(size_t)(n0 + n) * 1024 + k0 + c] = o;
    }
  } else {
    const int idx = (bid - 9216) * 256 + t;
    if (idx < 2047) {
      const int rel = idx - 1023;
      int bucket = (rel > 0) ? 16 : 0;
      const int rp = rel < 0 ? -rel : rel;
      if (rp < 8) {
        bucket += rp;
      } else {
        const double lv = log((double)rp / 8.0) / log(16.0) * 8.0;
        int large = 8 + (int)lv;
        bucket += (large < 15) ? large : 15;
      }
      #pragma unroll
      for (int h = 0; h < 16; ++h)
        btab[h * 2048 + idx] = rel_embed[bucket * 16 + h];
    }
  }
}

// ---------------------------------------------------------------------------
// Shared GEMM core (validated 2-barrier structure, unchanged).
// ---------------------------------------------------------------------------
template <int SWAP>
__device__ __forceinline__ void gemm_core(
    const unsigned short* __restrict__ A, const unsigned short* __restrict__ Bt,
    unsigned short* As, unsigned short* Bs, const int m0, const int n0,
    f32x4 acc[4][4]) {
  const int t = threadIdx.x, w = t >> 6, l = t & 63;
  const int lr = l & 15, lg = l >> 4;
  const int wr = w >> 1, wc = w & 1;

  const unsigned short* asrc[4];
  const unsigned short* bsrc[4];
  unsigned short* adst[4];
  unsigned short* bdst[4];
  #pragma unroll
  for (int i = 0; i < 4; ++i) {
    const int p = (w * 4 + i) * 64 + l, r = p >> 3, c = p & 7;
    const int cs = c ^ (r & 7);
    asrc[i] = A + (size_t)(m0 + r) * 1024 + cs * 8;
    bsrc[i] = Bt + (size_t)(n0 + r) * 1024 + cs * 8;
    adst[i] = &As[(w * 4 + i) * 512];
    bdst[i] = &Bs[(w * 4 + i) * 512];
  }

  int offA[2][4], offB[2][4];
  #pragma unroll
  for (int ks = 0; ks < 2; ++ks)
    #pragma unroll
    for (int mt = 0; mt < 4; ++mt) {
      offA[ks][mt] = (wr * 64 + mt * 16 + lr) * 64 + ((ks * 4 + lg) ^ (lr & 7)) * 8;
      offB[ks][mt] = (wc * 64 + mt * 16 + lr) * 64 + ((ks * 4 + lg) ^ (lr & 7)) * 8;
    }

  for (int k0 = 0; k0 < 16; ++k0) {
    #pragma unroll
    for (int i = 0; i < 4; ++i) {
      async_ld16(asrc[i], adst[i]);
      async_ld16(bsrc[i], bdst[i]);
      asrc[i] += 64;
      bsrc[i] += 64;
    }
    __syncthreads();
    #pragma unroll
    for (int ks = 0; ks < 2; ++ks) {
      short8 af[4], bf[4];
      #pragma unroll
      for (int mt = 0; mt < 4; ++mt) af[mt] = *(const short8*)&As[offA[ks][mt]];
      #pragma unroll
      for (int nt = 0; nt < 4; ++nt) bf[nt] = *(const short8*)&Bs[offB[ks][nt]];
      #pragma unroll
      for (int mt = 0; mt < 4; ++mt)
        #pragma unroll
        for (int nt = 0; nt < 4; ++nt)
          acc[mt][nt] = SWAP
              ? __builtin_amdgcn_mfma_f32_16x16x32_bf16(bf[nt], af[mt], acc[mt][nt], 0, 0, 0)
              : __builtin_amdgcn_mfma_f32_16x16x32_bf16(af[mt], bf[nt], acc[mt][nt], 0, 0, 0);
    }
    __syncthreads();
  }
}

// ---------------------------------------------------------------------------
// Fused QKV GEMM.  VGPR capped for 5 blocks/CU (was 108 -> 4 blocks).
// ---------------------------------------------------------------------------
__global__ __launch_bounds__(256, 5) void gemm_qkv(
    const unsigned short* __restrict__ A, const unsigned short* __restrict__ wt_all,
    const float* __restrict__ bq, const float* __restrict__ bk,
    const float* __restrict__ bv, unsigned short* __restrict__ q_ws,
    unsigned short* __restrict__ k_ws, unsigned short* __restrict__ vt_ws) {
  __shared__ __align__(16) unsigned short As[128 * 64];
  __shared__ __align__(16) unsigned short Bs[128 * 64];
  const int which = blockIdx.y >> 3;
  const int m0 = blockIdx.x * 128, n0 = (blockIdx.y & 7) * 128;
  const unsigned short* Bt = wt_all + (size_t)which * 1048576;

  const int t = threadIdx.x, w = t >> 6, l = t & 63;
  const int lr = l & 15, lg = l >> 4;
  const int wr = w >> 1, wc = w & 1;
  const int mbase = m0 + wr * 64, nbase = n0 + wc * 64;

  f32x4 acc[4][4];
  #pragma unroll
  for (int mt = 0; mt < 4; ++mt)
    #pragma unroll
    for (int nt = 0; nt < 4; ++nt) acc[mt][nt] = (f32x4){0.f, 0.f, 0.f, 0.f};

  if (which == 2) {
    gemm_core<0>(A, Bt, As, Bs, m0, n0, acc);
    #pragma unroll
    for (int mt = 0; mt < 4; ++mt) {
      const int m4 = mbase + mt * 16 + lg * 4;
      const int b = m4 >> 10, s = m4 & 1023;
      #pragma unroll
      for (int nt = 0; nt < 4; ++nt) {
        const int n = nbase + nt * 16 + lr, h = n >> 6, d = n & 63;
        const float bvv = bv[n];
        ushort4 o;
        o.x = f2bf(acc[mt][nt][0] + bvv);
        o.y = f2bf(acc[mt][nt][1] + bvv);
        o.z = f2bf(acc[mt][nt][2] + bvv);
        o.w = f2bf(acc[mt][nt][3] + bvv);
        *(ushort4*)&vt_ws[(size_t)(b * 16 + h) * 65536 + (size_t)d * 1024 + s] = o;
      }
    }
  } else {
    gemm_core<1>(A, Bt, As, Bs, m0, n0, acc);
    unsigned short* dst = (which == 0) ? q_ws : k_ws;
    const float* bias = (which == 0) ? bq : bk;
    const float scale = (which == 0) ? 0.18033688011f : 1.0f;  // 0.125*log2e
    #pragma unroll
    for (int nt = 0; nt < 4; ++nt) {
      const int n4 = nbase + nt * 16 + lg * 4;
      const int h = n4 >> 6, d = n4 & 63;
      const float4 b4 = *(const float4*)&bias[n4];
      #pragma unroll
      for (int mt = 0; mt < 4; ++mt) {
        const int m = mbase + mt * 16 + lr;
        const int b = m >> 10, s = m & 1023;
        ushort4 o;
        o.x = f2bf((acc[mt][nt][0] + b4.x) * scale);
        o.y = f2bf((acc[mt][nt][1] + b4.y) * scale);
        o.z = f2bf((acc[mt][nt][2] + b4.z) * scale);
        o.w = f2bf((acc[mt][nt][3] + b4.w) * scale);
        *(ushort4*)&dst[(size_t)(b * 16 + h) * 65536 + s * 64 + d] = o;
      }
    }
  }
}

// ---------------------------------------------------------------------------
// Output projection GEMM (unchanged, validated).
// ---------------------------------------------------------------------------
__global__ __launch_bounds__(256) void gemm_out(
    const unsigned short* __restrict__ A, const unsigned short* __restrict__ Bt,
    const float* __restrict__ bias, float* __restrict__ C) {
  __shared__ __align__(16) unsigned short As[128 * 64];
  __shared__ __align__(16) unsigned short Bs[128 * 64];
  const int m0 = blockIdx.x * 128, n0 = blockIdx.y * 128;
  f32x4 acc[4][4];
  #pragma unroll
  for (int mt = 0; mt < 4; ++mt)
    #pragma unroll
    for (int nt = 0; nt < 4; ++nt) acc[mt][nt] = (f32x4){0.f, 0.f, 0.f, 0.f};
  gemm_core<1>(A, Bt, As, Bs, m0, n0, acc);

  const int t = threadIdx.x, w = t >> 6, l = t & 63;
  const int lr = l & 15, lg = l >> 4;
  const int wr = w >> 1, wc = w & 1;
  const int mbase = m0 + wr * 64, nbase = n0 + wc * 64;
  #pragma unroll
  for (int nt = 0; nt < 4; ++nt) {
    const int n4 = nbase + nt * 16 + lg * 4;
    const float4 b4 = *(const float4*)&bias[n4];
    #pragma unroll
    for (int mt = 0; mt < 4; ++mt) {
      const int m = mbase + mt * 16 + lr;
      float4 o;
      o.x = acc[mt][nt][0] + b4.x;
      o.y = acc[mt][nt][1] + b4.y;
      o.z = acc[mt][nt][2] + b4.z;
      o.w = acc[mt][nt][3] + b4.w;
      *(float4*)&C[(size_t)m * 1024 + n4] = o;
    }
  }
}

// ---------------------------------------------------------------------------
// MFMA flash attention v5: 128 q rows/block, 8 waves (512 thr).
// K & V single-buffered (LDS 37.25 KB -> 4 blocks/CU = 32 waves/CU,
// grid 1024 = exact single round). Q in regs, bias as MFMA C-init,
// exp2 softmax, deferred lsum, defer-max, setprio MFMA clusters.
// ---------------------------------------------------------------------------
__global__ __launch_bounds__(512) void attn_mfma(
    const unsigned short* __restrict__ q_ws, const unsigned short* __restrict__ k_ws,
    const unsigned short* __restrict__ vt_ws, const float* __restrict__ gate_ws,
    const float* __restrict__ btab, unsigned short* __restrict__ ctx) {
  __shared__ __align__(16) unsigned short Ks[64 * 64];   // 8 KB
  __shared__ __align__(16) unsigned short Vts[64 * 64];  // 8 KB
  __shared__ __align__(16) unsigned short Ps[8 * 1024];  // 16 KB (2KB/wave)
  __shared__ __align__(16) float biasl[1216];            // 4.75 KB
  __shared__ float scl[128];                             // 0.5 KB

  const int t = threadIdx.x, w = t >> 6, l = t & 63;
  const int lr = l & 15, lg = l >> 4;
  const int bh = blockIdx.x, h = bh & 15, b = bh >> 4;
  const int q0 = blockIdx.y * 128;
  const size_t hb = (size_t)bh * 65536;

  // --- Q fragments direct from global (q pre-scaled by 0.125*log2e) -------
  short8 qf[2];
  #pragma unroll
  for (int ks = 0; ks < 2; ++ks)
    qf[ks] = *(const short8*)(q_ws + hb + (size_t)(q0 + w * 16 + lr) * 64 +
                              (ks * 4 + lg) * 8);

  // --- bias slice + per-thread gate ---------------------------------------
  {
    const float* bt = btab + h * 2048 + (896 - q0);
    const int u = t * 4;
    if (u < 1216) *(float4*)&biasl[u] = *(const float4*)&bt[u];
  }
  const float gtl = gate_ws[bh * 1024 + q0 + w * 16 + lr] * 1.44269504f;
  __syncthreads();  // biasl visible

  // --- per-lane offsets ----------------------------------------------------
  int pwoff[4], proff[2], offF[2][4];
  #pragma unroll
  for (int nt = 0; nt < 4; ++nt)
    pwoff[nt] = w * 2048 + ((lr * 128 + nt * 32 + lg * 8) ^ ((lr & 7) << 4));
  #pragma unroll
  for (int ks = 0; ks < 2; ++ks) {
    proff[ks] = w * 2048 + ((lr * 128 + ks * 64 + lg * 16) ^ ((lr & 7) << 4));
    #pragma unroll
    for (int nt = 0; nt < 4; ++nt)
      offF[ks][nt] = (nt * 16 + lr) * 64 + ((ks * 4 + lg) ^ (lr & 7)) * 8;
  }

  // --- staging addresses (src-swizzled; 512 thr cover each 8KB buffer) ----
  const int sr = t >> 3, scz = (t & 7) ^ (sr & 7);
  const unsigned short* ksrc0 = k_ws + hb + (size_t)sr * 64 + scz * 8;
  const unsigned short* vsrc0 = vt_ws + hb + (size_t)sr * 1024 + scz * 8;
  unsigned short* kdst = &Ks[w * 512];
  unsigned short* vdst = &Vts[w * 512];

  float mcur = -1e30f, lsum = 0.f;  // lsum: per-lane partial (reduced at end)
  f32x4 acc_o[4];
  #pragma unroll
  for (int dt = 0; dt < 4; ++dt) acc_o[dt] = (f32x4){0.f, 0.f, 0.f, 0.f};
  const int ub = 127 - w * 16 - lr;
  char* Pb = (char*)Ps;

  for (int kt = 0; kt < 16; ++kt) {
    // ---- stage K(kt), V(kt) (WAR-safe: prev iter ended with a barrier) ---
    async_ld16(ksrc0 + kt * 4096, kdst);
    async_ld16(vsrc0 + kt * 64, vdst);

    // ---- C-init = gate*bias (hides under the staging drain) --------------
    const int bb = kt * 64 + ub + lg * 4;
    f32x4 accs[4];
    #pragma unroll
    for (int nt = 0; nt < 4; ++nt) {
      accs[nt][0] = gtl * biasl[bb + nt * 16 + 0];
      accs[nt][1] = gtl * biasl[bb + nt * 16 + 1];
      accs[nt][2] = gtl * biasl[bb + nt * 16 + 2];
      accs[nt][3] = gtl * biasl[bb + nt * 16 + 3];
    }

    // ---- drain: K/V landed block-wide ------------------------------------
    asm volatile("s_waitcnt vmcnt(0) lgkmcnt(0)" ::: "memory");
    __builtin_amdgcn_s_barrier();
    __builtin_amdgcn_sched_barrier(0);

    // ---- QK^T swapped: accs[nt][i] += S^T[k=nt*16+lg*4+i][q=lr] ----------
    __builtin_amdgcn_s_setprio(1);
    #pragma unroll
    for (int ks = 0; ks < 2; ++ks) {
      #pragma unroll
      for (int nt = 0; nt < 4; ++nt) {
        const short8 kf = *(const short8*)&Ks[offF[ks][nt]];
        accs[nt] = __builtin_amdgcn_mfma_f32_16x16x32_bf16(kf, qf[ks], accs[nt], 0, 0, 0);
      }
    }
    __builtin_amdgcn_s_setprio(0);

    // ---- per-lane row max ------------------------------------------------
    float tm = -1e30f;
    #pragma unroll
    for (int nt = 0; nt < 4; ++nt)
      tm = fmaxf(fmaxf(tm, fmaxf(accs[nt][0], accs[nt][1])),
                 fmaxf(accs[nt][2], accs[nt][3]));
    tm = fmaxf(tm, __shfl_xor(tm, 16));
    tm = fmaxf(tm, __shfl_xor(tm, 32));

    const int skip = __all(tm <= mcur + 11.5f);  // defer-max (log2 units)
    float sc = 1.0f;
    if (!skip) {
      const float mn = fmaxf(mcur, tm);
      sc = EXP2(mcur - mn);
      mcur = mn;
      if (lg == 0) scl[w * 16 + lr] = sc;
    }

    // ---- p = exp2(sv - mcur), pack bf16, write P, partial row sum --------
    float ps = 0.f;
    #pragma unroll
    for (int nt = 0; nt < 4; ++nt) {
      const float p0 = EXP2(accs[nt][0] - mcur);
      const float p1 = EXP2(accs[nt][1] - mcur);
      const float p2 = EXP2(accs[nt][2] - mcur);
      const float p3 = EXP2(accs[nt][3] - mcur);
      ps += (p0 + p1) + (p2 + p3);
      short4 pk;
      pk.x = (short)f2bf(p0); pk.y = (short)f2bf(p1);
      pk.z = (short)f2bf(p2); pk.w = (short)f2bf(p3);
      *(short4*)(Pb + pwoff[nt]) = pk;
    }
    lsum = skip ? (lsum + ps) : (lsum * sc + ps);

    // ---- P/scl visible to own wave (wave-private; rule-18 fence) ---------
    asm volatile("s_waitcnt lgkmcnt(0)" ::: "memory");
    __builtin_amdgcn_sched_barrier(0);

    // ---- rescale acc_o (only when max moved) -----------------------------
    if (!skip) {
      const float s0 = scl[w * 16 + lg * 4 + 0];
      const float s1 = scl[w * 16 + lg * 4 + 1];
      const float s2 = scl[w * 16 + lg * 4 + 2];
      const float s3 = scl[w * 16 + lg * 4 + 3];
      #pragma unroll
      for (int dt = 0; dt < 4; ++dt) {
        acc_o[dt][0] *= s0; acc_o[dt][1] *= s1;
        acc_o[dt][2] *= s2; acc_o[dt][3] *= s3;
      }
    }

    // ---- PV: O[q][d] += P[q][k] V[k][d] ----------------------------------
    __builtin_amdgcn_s_setprio(1);
    #pragma unroll
    for (int ks = 0; ks < 2; ++ks) {
      const short8 pf = *(const short8*)(Pb + proff[ks]);
      #pragma unroll
      for (int dt = 0; dt < 4; ++dt) {
        const short8 vf = *(const short8*)&Vts[offF[ks][dt]];
        acc_o[dt] = __builtin_amdgcn_mfma_f32_16x16x32_bf16(pf, vf, acc_o[dt], 0, 0, 0);
      }
    }
    __builtin_amdgcn_s_setprio(0);

    // ---- WAR barrier: all waves done reading Ks/Vts before next stage ----
    asm volatile("s_waitcnt lgkmcnt(0)" ::: "memory");
    __builtin_amdgcn_s_barrier();
    __builtin_amdgcn_sched_barrier(0);
  }

  // ---- epilogue: reduce partial lsum across the 4 lanes of each q-row ----
  lsum += __shfl_xor(lsum, 16);
  lsum += __shfl_xor(lsum, 32);
  if (lg == 0) scl[w * 16 + lr] = 1.0f / lsum;
  asm volatile("s_waitcnt lgkmcnt(0)" ::: "memory");
  __builtin_amdgcn_sched_barrier(0);
  float inv[4];
  #pragma unroll
  for (int i = 0; i < 4; ++i) inv[i] = scl[w * 16 + lg * 4 + i];
  #pragma unroll
  for (int i = 0; i < 4; ++i) {
    const int q = q0 + w * 16 + lg * 4 + i;
    const size_t rowoff = ((size_t)(b * 1024 + q) * 16 + h) * 64;
    #pragma unroll
    for (int dt = 0; dt < 4; ++dt)
      ctx[rowoff + dt * 16 + lr] = f2bf(acc_o[dt][i] * inv[i]);
  }
}

// ---------------------------------------------------------------------------
extern "C" void kernel_launch(void* const* d_in, const int* in_sizes, int n_in,
                              void* d_out, int out_size, void* d_ws, size_t ws_size,
                              hipStream_t stream) {
  const float* x    = (const float*)d_in[0];
  const float* Wq   = (const float*)d_in[1];
  const float* bq   = (const float*)d_in[2];
  const float* Wk   = (const float*)d_in[3];
  const float* bk   = (const float*)d_in[4];
  const float* Wv   = (const float*)d_in[5];
  const float* bv   = (const float*)d_in[6];
  const float* Wo   = (const float*)d_in[7];
  const float* bo   = (const float*)d_in[8];
  const float* rel  = (const float*)d_in[9];
  const float* gw   = (const float*)d_in[10];
  const float* gb   = (const float*)d_in[11];
  const float* gcst = (const float*)d_in[12];
  float* out = (float*)d_out;

  char* ws = (char*)d_ws;
  unsigned short* x_bf   = (unsigned short*)(ws);
  unsigned short* wt_all = (unsigned short*)(ws + 16777216);
  unsigned short* q_ws   = (unsigned short*)(ws + 25165824);
  unsigned short* k_ws   = (unsigned short*)(ws + 41943040);
  unsigned short* vt_ws  = (unsigned short*)(ws + 58720256);
  unsigned short* ctx    = (unsigned short*)(ws + 75497472);
  float* gate = (float*)(ws + 92274688);
  float* btab = (float*)(ws + 92798976);

  prep_all <<<dim3(9224),   256, 0, stream>>>(x, gw, gb, gcst, Wq, Wk, Wv, Wo,
                                              rel, x_bf, gate, wt_all, btab);
  gemm_qkv <<<dim3(64, 24), 256, 0, stream>>>(x_bf, wt_all, bq, bk, bv,
                                              q_ws, k_ws, vt_ws);
  attn_mfma<<<dim3(128, 8), 512, 0, stream>>>(q_ws, k_ws, vt_ws, gate, btab, ctx);
  gemm_out <<<dim3(64, 8),  256, 0, stream>>>(ctx, wt_all + 3 * 1048576, bo, out);
}

// Round 7
// 281.953 us; speedup vs baseline: 1.3867x; 1.3867x over previous
//
#include <hip/hip_runtime.h>
#include <hip/hip_bf16.h>
#include <math.h>

// ---------------------------------------------------------------------------
// WavLM self-attention, bf16-MFMA v5r (round-7: revert of the round-6
// launch_bounds regression; attn v5 kept).
//   B=8 S=1024 H=16 D=64 E=1024; q pre-scaled by 0.125*log2(e) (exp2 softmax)
// Round-7 changes vs round-6:
//   * gemm_qkv: __launch_bounds__(256) (REVERT -- (256,5) made the allocator
//     pick 48 VGPR and spill: FETCH 49->300MB, 72.5->182us. Do not re-apply.)
//   * everything else byte-identical to round 6 (attn v5 single-buffered,
//     4 blocks/CU, measured ~neutral-to-slightly-better vs v4).
// Workspace (bytes): same layout as rounds 3-6.
// ---------------------------------------------------------------------------

typedef __attribute__((ext_vector_type(8))) short short8;
typedef __attribute__((ext_vector_type(4))) float f32x4;

#define LDSP(p) ((__attribute__((address_space(3))) void*)(p))
#define GLBP(p) ((const __attribute__((address_space(1))) void*)(p))

__device__ __forceinline__ void async_ld16(const void* src, void* dst) {
  __builtin_amdgcn_global_load_lds(GLBP(src), LDSP(dst), 16, 0, 0);
}
__device__ __forceinline__ unsigned short f2bf(float f) {
  __hip_bfloat16 h = __float2bfloat16(f);
  return __builtin_bit_cast(unsigned short, h);
}
#if __has_builtin(__builtin_amdgcn_exp2f)
#define EXP2(x) __builtin_amdgcn_exp2f(x)
#else
#define EXP2(x) exp2f(x)
#endif

// ---------------------------------------------------------------------------
// Fused prep: [0,8192) cvt+gate, [8192,9216) transW x4, [9216,9224) btab.
// (unchanged, validated)
// ---------------------------------------------------------------------------
__global__ __launch_bounds__(256) void prep_all(
    const float* __restrict__ x, const float* __restrict__ gw,
    const float* __restrict__ gb, const float* __restrict__ gcst,
    const float* __restrict__ W0, const float* __restrict__ W1,
    const float* __restrict__ W2, const float* __restrict__ W3,
    const float* __restrict__ rel_embed,
    unsigned short* __restrict__ xb, float* __restrict__ gate_ws,
    unsigned short* __restrict__ Wt_all, float* __restrict__ btab) {
  __shared__ __align__(16) float tile[64][68];
  const int bid = blockIdx.x, t = threadIdx.x;
  if (bid < 8192) {
    float* xr = &tile[0][0];
    const float4 v = *(const float4*)&x[(size_t)bid * 1024 + t * 4];
    *(float4*)&xr[t * 4] = v;
    ushort4 o;
    o.x = f2bf(v.x); o.y = f2bf(v.y); o.z = f2bf(v.z); o.w = f2bf(v.w);
    *(ushort4*)&xb[(size_t)bid * 1024 + t * 4] = o;
    __syncthreads();
    const int h = t >> 4, i = t & 15;
    float pa = 0.f, pb = 0.f;
    #pragma unroll
    for (int j = 0; j < 4; ++j) {
      const int d = i * 4 + j;
      const float xv = xr[h * 64 + d];
      const float* wr = &gw[d * 8];
      pa += xv * (wr[0] + wr[1] + wr[2] + wr[3]);
      pb += xv * (wr[4] + wr[5] + wr[6] + wr[7]);
    }
    #pragma unroll
    for (int msk = 1; msk <= 8; msk <<= 1) {
      pa += __shfl_xor(pa, msk);
      pb += __shfl_xor(pb, msk);
    }
    if (i == 0) {
      const float ba = gb[0] + gb[1] + gb[2] + gb[3];
      const float bb = gb[4] + gb[5] + gb[6] + gb[7];
      const float ga  = 1.f / (1.f + __expf(-(pa + ba)));
      const float gbv = 1.f / (1.f + __expf(-(pb + bb)));
      const float gv  = ga * (gbv * gcst[h] - 1.f) + 2.f;
      const int b = bid >> 10, s = bid & 1023;
      gate_ws[(b * 16 + h) * 1024 + s] = gv;
    }
  } else if (bid < 9216) {
    const int zz = bid - 8192;
    const int z = zz >> 8;
    const float* W = (z == 0) ? W0 : (z == 1) ? W1 : (z == 2) ? W2 : W3;
    unsigned short* Wt = Wt_all + (size_t)z * 1048576;
    const int n0 = (zz & 15) * 64, k0 = ((zz >> 4) & 15) * 64;
    const int c = (t & 15) * 4, r = t >> 4;
    #pragma unroll
    for (int i = 0; i < 4; ++i)
      *(float4*)&tile[r + i * 16][c] =
          *(const float4*)&W[(size_t)(k0 + r + i * 16) * 1024 + n0 + c];
    __syncthreads();
    #pragma unroll
    for (int i = 0; i < 4; ++i) {
      const int n = r + i * 16;
      ushort4 o;
      o.x = f2bf(tile[c + 0][n]); o.y = f2bf(tile[c + 1][n]);
      o.z = f2bf(tile[c + 2][n]); o.w = f2bf(tile[c + 3][n]);
      *(ushort4*)&Wt[(size_t)(n0 + n) * 1024 + k0 + c] = o;
    }
  } else {
    const int idx = (bid - 9216) * 256 + t;
    if (idx < 2047) {
      const int rel = idx - 1023;
      int bucket = (rel > 0) ? 16 : 0;
      const int rp = rel < 0 ? -rel : rel;
      if (rp < 8) {
        bucket += rp;
      } else {
        const double lv = log((double)rp / 8.0) / log(16.0) * 8.0;
        int large = 8 + (int)lv;
        bucket += (large < 15) ? large : 15;
      }
      #pragma unroll
      for (int h = 0; h < 16; ++h)
        btab[h * 2048 + idx] = rel_embed[bucket * 16 + h];
    }
  }
}

// ---------------------------------------------------------------------------
// Shared GEMM core (validated 2-barrier structure, unchanged).
// ---------------------------------------------------------------------------
template <int SWAP>
__device__ __forceinline__ void gemm_core(
    const unsigned short* __restrict__ A, const unsigned short* __restrict__ Bt,
    unsigned short* As, unsigned short* Bs, const int m0, const int n0,
    f32x4 acc[4][4]) {
  const int t = threadIdx.x, w = t >> 6, l = t & 63;
  const int lr = l & 15, lg = l >> 4;
  const int wr = w >> 1, wc = w & 1;

  const unsigned short* asrc[4];
  const unsigned short* bsrc[4];
  unsigned short* adst[4];
  unsigned short* bdst[4];
  #pragma unroll
  for (int i = 0; i < 4; ++i) {
    const int p = (w * 4 + i) * 64 + l, r = p >> 3, c = p & 7;
    const int cs = c ^ (r & 7);
    asrc[i] = A + (size_t)(m0 + r) * 1024 + cs * 8;
    bsrc[i] = Bt + (size_t)(n0 + r) * 1024 + cs * 8;
    adst[i] = &As[(w * 4 + i) * 512];
    bdst[i] = &Bs[(w * 4 + i) * 512];
  }

  int offA[2][4], offB[2][4];
  #pragma unroll
  for (int ks = 0; ks < 2; ++ks)
    #pragma unroll
    for (int mt = 0; mt < 4; ++mt) {
      offA[ks][mt] = (wr * 64 + mt * 16 + lr) * 64 + ((ks * 4 + lg) ^ (lr & 7)) * 8;
      offB[ks][mt] = (wc * 64 + mt * 16 + lr) * 64 + ((ks * 4 + lg) ^ (lr & 7)) * 8;
    }

  for (int k0 = 0; k0 < 16; ++k0) {
    #pragma unroll
    for (int i = 0; i < 4; ++i) {
      async_ld16(asrc[i], adst[i]);
      async_ld16(bsrc[i], bdst[i]);
      asrc[i] += 64;
      bsrc[i] += 64;
    }
    __syncthreads();
    #pragma unroll
    for (int ks = 0; ks < 2; ++ks) {
      short8 af[4], bf[4];
      #pragma unroll
      for (int mt = 0; mt < 4; ++mt) af[mt] = *(const short8*)&As[offA[ks][mt]];
      #pragma unroll
      for (int nt = 0; nt < 4; ++nt) bf[nt] = *(const short8*)&Bs[offB[ks][nt]];
      #pragma unroll
      for (int mt = 0; mt < 4; ++mt)
        #pragma unroll
        for (int nt = 0; nt < 4; ++nt)
          acc[mt][nt] = SWAP
              ? __builtin_amdgcn_mfma_f32_16x16x32_bf16(bf[nt], af[mt], acc[mt][nt], 0, 0, 0)
              : __builtin_amdgcn_mfma_f32_16x16x32_bf16(af[mt], bf[nt], acc[mt][nt], 0, 0, 0);
    }
    __syncthreads();
  }
}

// ---------------------------------------------------------------------------
// Fused QKV GEMM (plain launch_bounds -- see round-6 post-mortem; do NOT
// add a min-blocks argument here, it spills).
// ---------------------------------------------------------------------------
__global__ __launch_bounds__(256) void gemm_qkv(
    const unsigned short* __restrict__ A, const unsigned short* __restrict__ wt_all,
    const float* __restrict__ bq, const float* __restrict__ bk,
    const float* __restrict__ bv, unsigned short* __restrict__ q_ws,
    unsigned short* __restrict__ k_ws, unsigned short* __restrict__ vt_ws) {
  __shared__ __align__(16) unsigned short As[128 * 64];
  __shared__ __align__(16) unsigned short Bs[128 * 64];
  const int which = blockIdx.y >> 3;
  const int m0 = blockIdx.x * 128, n0 = (blockIdx.y & 7) * 128;
  const unsigned short* Bt = wt_all + (size_t)which * 1048576;

  const int t = threadIdx.x, w = t >> 6, l = t & 63;
  const int lr = l & 15, lg = l >> 4;
  const int wr = w >> 1, wc = w & 1;
  const int mbase = m0 + wr * 64, nbase = n0 + wc * 64;

  f32x4 acc[4][4];
  #pragma unroll
  for (int mt = 0; mt < 4; ++mt)
    #pragma unroll
    for (int nt = 0; nt < 4; ++nt) acc[mt][nt] = (f32x4){0.f, 0.f, 0.f, 0.f};

  if (which == 2) {
    gemm_core<0>(A, Bt, As, Bs, m0, n0, acc);
    #pragma unroll
    for (int mt = 0; mt < 4; ++mt) {
      const int m4 = mbase + mt * 16 + lg * 4;
      const int b = m4 >> 10, s = m4 & 1023;
      #pragma unroll
      for (int nt = 0; nt < 4; ++nt) {
        const int n = nbase + nt * 16 + lr, h = n >> 6, d = n & 63;
        const float bvv = bv[n];
        ushort4 o;
        o.x = f2bf(acc[mt][nt][0] + bvv);
        o.y = f2bf(acc[mt][nt][1] + bvv);
        o.z = f2bf(acc[mt][nt][2] + bvv);
        o.w = f2bf(acc[mt][nt][3] + bvv);
        *(ushort4*)&vt_ws[(size_t)(b * 16 + h) * 65536 + (size_t)d * 1024 + s] = o;
      }
    }
  } else {
    gemm_core<1>(A, Bt, As, Bs, m0, n0, acc);
    unsigned short* dst = (which == 0) ? q_ws : k_ws;
    const float* bias = (which == 0) ? bq : bk;
    const float scale = (which == 0) ? 0.18033688011f : 1.0f;  // 0.125*log2e
    #pragma unroll
    for (int nt = 0; nt < 4; ++nt) {
      const int n4 = nbase + nt * 16 + lg * 4;
      const int h = n4 >> 6, d = n4 & 63;
      const float4 b4 = *(const float4*)&bias[n4];
      #pragma unroll
      for (int mt = 0; mt < 4; ++mt) {
        const int m = mbase + mt * 16 + lr;
        const int b = m >> 10, s = m & 1023;
        ushort4 o;
        o.x = f2bf((acc[mt][nt][0] + b4.x) * scale);
        o.y = f2bf((acc[mt][nt][1] + b4.y) * scale);
        o.z = f2bf((acc[mt][nt][2] + b4.z) * scale);
        o.w = f2bf((acc[mt][nt][3] + b4.w) * scale);
        *(ushort4*)&dst[(size_t)(b * 16 + h) * 65536 + s * 64 + d] = o;
      }
    }
  }
}

// ---------------------------------------------------------------------------
// Output projection GEMM (unchanged, validated).
// ---------------------------------------------------------------------------
__global__ __launch_bounds__(256) void gemm_out(
    const unsigned short* __restrict__ A, const unsigned short* __restrict__ Bt,
    const float* __restrict__ bias, float* __restrict__ C) {
  __shared__ __align__(16) unsigned short As[128 * 64];
  __shared__ __align__(16) unsigned short Bs[128 * 64];
  const int m0 = blockIdx.x * 128, n0 = blockIdx.y * 128;
  f32x4 acc[4][4];
  #pragma unroll
  for (int mt = 0; mt < 4; ++mt)
    #pragma unroll
    for (int nt = 0; nt < 4; ++nt) acc[mt][nt] = (f32x4){0.f, 0.f, 0.f, 0.f};
  gemm_core<1>(A, Bt, As, Bs, m0, n0, acc);

  const int t = threadIdx.x, w = t >> 6, l = t & 63;
  const int lr = l & 15, lg = l >> 4;
  const int wr = w >> 1, wc = w & 1;
  const int mbase = m0 + wr * 64, nbase = n0 + wc * 64;
  #pragma unroll
  for (int nt = 0; nt < 4; ++nt) {
    const int n4 = nbase + nt * 16 + lg * 4;
    const float4 b4 = *(const float4*)&bias[n4];
    #pragma unroll
    for (int mt = 0; mt < 4; ++mt) {
      const int m = mbase + mt * 16 + lr;
      float4 o;
      o.x = acc[mt][nt][0] + b4.x;
      o.y = acc[mt][nt][1] + b4.y;
      o.z = acc[mt][nt][2] + b4.z;
      o.w = acc[mt][nt][3] + b4.w;
      *(float4*)&C[(size_t)m * 1024 + n4] = o;
    }
  }
}

// ---------------------------------------------------------------------------
// MFMA flash attention v5 (unchanged from round 6; measured ~neutral vs v4
// with 10 KB less LDS and 4 blocks/CU).
// ---------------------------------------------------------------------------
__global__ __launch_bounds__(512) void attn_mfma(
    const unsigned short* __restrict__ q_ws, const unsigned short* __restrict__ k_ws,
    const unsigned short* __restrict__ vt_ws, const float* __restrict__ gate_ws,
    const float* __restrict__ btab, unsigned short* __restrict__ ctx) {
  __shared__ __align__(16) unsigned short Ks[64 * 64];   // 8 KB
  __shared__ __align__(16) unsigned short Vts[64 * 64];  // 8 KB
  __shared__ __align__(16) unsigned short Ps[8 * 1024];  // 16 KB (2KB/wave)
  __shared__ __align__(16) float biasl[1216];            // 4.75 KB
  __shared__ float scl[128];                             // 0.5 KB

  const int t = threadIdx.x, w = t >> 6, l = t & 63;
  const int lr = l & 15, lg = l >> 4;
  const int bh = blockIdx.x, h = bh & 15, b = bh >> 4;
  const int q0 = blockIdx.y * 128;
  const size_t hb = (size_t)bh * 65536;

  // --- Q fragments direct from global (q pre-scaled by 0.125*log2e) -------
  short8 qf[2];
  #pragma unroll
  for (int ks = 0; ks < 2; ++ks)
    qf[ks] = *(const short8*)(q_ws + hb + (size_t)(q0 + w * 16 + lr) * 64 +
                              (ks * 4 + lg) * 8);

  // --- bias slice + per-thread gate ---------------------------------------
  {
    const float* bt = btab + h * 2048 + (896 - q0);
    const int u = t * 4;
    if (u < 1216) *(float4*)&biasl[u] = *(const float4*)&bt[u];
  }
  const float gtl = gate_ws[bh * 1024 + q0 + w * 16 + lr] * 1.44269504f;
  __syncthreads();  // biasl visible

  // --- per-lane offsets ----------------------------------------------------
  int pwoff[4], proff[2], offF[2][4];
  #pragma unroll
  for (int nt = 0; nt < 4; ++nt)
    pwoff[nt] = w * 2048 + ((lr * 128 + nt * 32 + lg * 8) ^ ((lr & 7) << 4));
  #pragma unroll
  for (int ks = 0; ks < 2; ++ks) {
    proff[ks] = w * 2048 + ((lr * 128 + ks * 64 + lg * 16) ^ ((lr & 7) << 4));
    #pragma unroll
    for (int nt = 0; nt < 4; ++nt)
      offF[ks][nt] = (nt * 16 + lr) * 64 + ((ks * 4 + lg) ^ (lr & 7)) * 8;
  }

  // --- staging addresses (src-swizzled; 512 thr cover each 8KB buffer) ----
  const int sr = t >> 3, scz = (t & 7) ^ (sr & 7);
  const unsigned short* ksrc0 = k_ws + hb + (size_t)sr * 64 + scz * 8;
  const unsigned short* vsrc0 = vt_ws + hb + (size_t)sr * 1024 + scz * 8;
  unsigned short* kdst = &Ks[w * 512];
  unsigned short* vdst = &Vts[w * 512];

  float mcur = -1e30f, lsum = 0.f;  // lsum: per-lane partial (reduced at end)
  f32x4 acc_o[4];
  #pragma unroll
  for (int dt = 0; dt < 4; ++dt) acc_o[dt] = (f32x4){0.f, 0.f, 0.f, 0.f};
  const int ub = 127 - w * 16 - lr;
  char* Pb = (char*)Ps;

  for (int kt = 0; kt < 16; ++kt) {
    // ---- stage K(kt), V(kt) (WAR-safe: prev iter ended with a barrier) ---
    async_ld16(ksrc0 + kt * 4096, kdst);
    async_ld16(vsrc0 + kt * 64, vdst);

    // ---- C-init = gate*bias (hides under the staging drain) --------------
    const int bb = kt * 64 + ub + lg * 4;
    f32x4 accs[4];
    #pragma unroll
    for (int nt = 0; nt < 4; ++nt) {
      accs[nt][0] = gtl * biasl[bb + nt * 16 + 0];
      accs[nt][1] = gtl * biasl[bb + nt * 16 + 1];
      accs[nt][2] = gtl * biasl[bb + nt * 16 + 2];
      accs[nt][3] = gtl * biasl[bb + nt * 16 + 3];
    }

    // ---- drain: K/V landed block-wide ------------------------------------
    asm volatile("s_waitcnt vmcnt(0) lgkmcnt(0)" ::: "memory");
    __builtin_amdgcn_s_barrier();
    __builtin_amdgcn_sched_barrier(0);

    // ---- QK^T swapped: accs[nt][i] += S^T[k=nt*16+lg*4+i][q=lr] ----------
    __builtin_amdgcn_s_setprio(1);
    #pragma unroll
    for (int ks = 0; ks < 2; ++ks) {
      #pragma unroll
      for (int nt = 0; nt < 4; ++nt) {
        const short8 kf = *(const short8*)&Ks[offF[ks][nt]];
        accs[nt] = __builtin_amdgcn_mfma_f32_16x16x32_bf16(kf, qf[ks], accs[nt], 0, 0, 0);
      }
    }
    __builtin_amdgcn_s_setprio(0);

    // ---- per-lane row max ------------------------------------------------
    float tm = -1e30f;
    #pragma unroll
    for (int nt = 0; nt < 4; ++nt)
      tm = fmaxf(fmaxf(tm, fmaxf(accs[nt][0], accs[nt][1])),
                 fmaxf(accs[nt][2], accs[nt][3]));
    tm = fmaxf(tm, __shfl_xor(tm, 16));
    tm = fmaxf(tm, __shfl_xor(tm, 32));

    const int skip = __all(tm <= mcur + 11.5f);  // defer-max (log2 units)
    float sc = 1.0f;
    if (!skip) {
      const float mn = fmaxf(mcur, tm);
      sc = EXP2(mcur - mn);
      mcur = mn;
      if (lg == 0) scl[w * 16 + lr] = sc;
    }

    // ---- p = exp2(sv - mcur), pack bf16, write P, partial row sum --------
    float ps = 0.f;
    #pragma unroll
    for (int nt = 0; nt < 4; ++nt) {
      const float p0 = EXP2(accs[nt][0] - mcur);
      const float p1 = EXP2(accs[nt][1] - mcur);
      const float p2 = EXP2(accs[nt][2] - mcur);
      const float p3 = EXP2(accs[nt][3] - mcur);
      ps += (p0 + p1) + (p2 + p3);
      short4 pk;
      pk.x = (short)f2bf(p0); pk.y = (short)f2bf(p1);
      pk.z = (short)f2bf(p2); pk.w = (short)f2bf(p3);
      *(short4*)(Pb + pwoff[nt]) = pk;
    }
    lsum = skip ? (lsum + ps) : (lsum * sc + ps);

    // ---- P/scl visible to own wave (wave-private; rule-18 fence) ---------
    asm volatile("s_waitcnt lgkmcnt(0)" ::: "memory");
    __builtin_amdgcn_sched_barrier(0);

    // ---- rescale acc_o (only when max moved) -----------------------------
    if (!skip) {
      const float s0 = scl[w * 16 + lg * 4 + 0];
      const float s1 = scl[w * 16 + lg * 4 + 1];
      const float s2 = scl[w * 16 + lg * 4 + 2];
      const float s3 = scl[w * 16 + lg * 4 + 3];
      #pragma unroll
      for (int dt = 0; dt < 4; ++dt) {
        acc_o[dt][0] *= s0; acc_o[dt][1] *= s1;
        acc_o[dt][2] *= s2; acc_o[dt][3] *= s3;
      }
    }

    // ---- PV: O[q][d] += P[q][k] V[k][d] ----------------------------------
    __builtin_amdgcn_s_setprio(1);
    #pragma unroll
    for (int ks = 0; ks < 2; ++ks) {
      const short8 pf = *(const short8*)(Pb + proff[ks]);
      #pragma unroll
      for (int dt = 0; dt < 4; ++dt) {
        const short8 vf = *(const short8*)&Vts[offF[ks][dt]];
        acc_o[dt] = __builtin_amdgcn_mfma_f32_16x16x32_bf16(pf, vf, acc_o[dt], 0, 0, 0);
      }
    }
    __builtin_amdgcn_s_setprio(0);

    // ---- WAR barrier: all waves done reading Ks/Vts before next stage ----
    asm volatile("s_waitcnt lgkmcnt(0)" ::: "memory");
    __builtin_amdgcn_s_barrier();
    __builtin_amdgcn_sched_barrier(0);
  }

  // ---- epilogue: reduce partial lsum across the 4 lanes of each q-row ----
  lsum += __shfl_xor(lsum, 16);
  lsum += __shfl_xor(lsum, 32);
  if (lg == 0) scl[w * 16 + lr] = 1.0f / lsum;
  asm volatile("s_waitcnt lgkmcnt(0)" ::: "memory");
  __builtin_amdgcn_sched_barrier(0);
  float inv[4];
  #pragma unroll
  for (int i = 0; i < 4; ++i) inv[i] = scl[w * 16 + lg * 4 + i];
  #pragma unroll
  for (int i = 0; i < 4; ++i) {
    const int q = q0 + w * 16 + lg * 4 + i;
    const size_t rowoff = ((size_t)(b * 1024 + q) * 16 + h) * 64;
    #pragma unroll
    for (int dt = 0; dt < 4; ++dt)
      ctx[rowoff + dt * 16 + lr] = f2bf(acc_o[dt][i] * inv[i]);
  }
}

// ---------------------------------------------------------------------------
extern "C" void kernel_launch(void* const* d_in, const int* in_sizes, int n_in,
                              void* d_out, int out_size, void* d_ws, size_t ws_size,
                              hipStream_t stream) {
  const float* x    = (const float*)d_in[0];
  const float* Wq   = (const float*)d_in[1];
  const float* bq   = (const float*)d_in[2];
  const float* Wk   = (const float*)d_in[3];
  const float* bk   = (const float*)d_in[4];
  const float* Wv   = (const float*)d_in[5];
  const float* bv   = (const float*)d_in[6];
  const float* Wo   = (const float*)d_in[7];
  const float* bo   = (const float*)d_in[8];
  const float* rel  = (const float*)d_in[9];
  const float* gw   = (const float*)d_in[10];
  const float* gb   = (const float*)d_in[11];
  const float* gcst = (const float*)d_in[12];
  float* out = (float*)d_out;

  char* ws = (char*)d_ws;
  unsigned short* x_bf   = (unsigned short*)(ws);
  unsigned short* wt_all = (unsigned short*)(ws + 16777216);
  unsigned short* q_ws   = (unsigned short*)(ws + 25165824);
  unsigned short* k_ws   = (unsigned short*)(ws + 41943040);
  unsigned short* vt_ws  = (unsigned short*)(ws + 58720256);
  unsigned short* ctx    = (unsigned short*)(ws + 75497472);
  float* gate = (float*)(ws + 92274688);
  float* btab = (float*)(ws + 92798976);

  prep_all <<<dim3(9224),   256, 0, stream>>>(x, gw, gb, gcst, Wq, Wk, Wv, Wo,
                                              rel, x_bf, gate, wt_all, btab);
  gemm_qkv <<<dim3(64, 24), 256, 0, stream>>>(x_bf, wt_all, bq, bk, bv,
                                              q_ws, k_ws, vt_ws);
  attn_mfma<<<dim3(128, 8), 512, 0, stream>>>(q_ws, k_ws, vt_ws, gate, btab, ctx);
  gemm_out <<<dim3(64, 8),  256, 0, stream>>>(ctx, wt_all + 3 * 1048576, bo, out);
}